// Round 7
// baseline (33.744 us; speedup 1.0000x reference)
//
#include <hip/hip_runtime.h>
#include <hip/hip_bf16.h>

// Shapes: x,gn (8,128,64) f32; fb (1,128,32768) f32; resonance (64,128) f32.
// out (8,1,32768) f32.
// r[b,c,f] = sum_rr softmax(x+gn)[b,c,rr] * res[rr,f]
// out[b,s] = (1/128) * sum_c lerp(r[b,c,:], s) * fb[c,s]
//
// Single kernel, block-local sync only.
//  - R4 (grid barrier): agent-scope fences -> ~90us L2 writeback storms. Dead.
//  - R5 (fused, v[64] per thread): VGPR spills under launch_bounds cap. Dead.
//  - R7: same fusion as R5 but ONLINE softmax + fused dual-dot: ~24 live
//    VGPRs, no spills. Each block redundantly softmaxes all 1024 rows
//    (512 KB x+gn re-read per block, L2-served; 16 MB/XCD ~= 3.7us).
// Block k owns samples [128k, 128k+127], all 8 batches. floor(pos) is
// block-uniform (crossings at s = 256m+127.5 sit between 128-aligned
// segments), so exactly 2 frames (f0,f1) are needed -> r_s/dd_s in LDS.

#define BATCH 8
#define BANDS 128
#define RES 64
#define NF 128
#define NS 32768
#define NBC (BATCH * BANDS)   // 1024
#define SEG 128
#define NBLK (NS / SEG)       // 256 = 1 block/CU
#define NTHR 1024

__global__ __launch_bounds__(NTHR) void fused(const float* __restrict__ x,
                                              const float* __restrict__ gn,
                                              const float* __restrict__ fb,
                                              const float* __restrict__ res,
                                              float* __restrict__ out) {
    const int k   = blockIdx.x;      // segment 0..255
    const int tid = threadIdx.x;     // 0..1023

    __shared__ float4 resc0[RES / 4];   // res column f0
    __shared__ float4 resc1[RES / 4];   // res column f1
    __shared__ float  r_s[NBC];
    __shared__ float  dd_s[NBC];

    // ---- block-uniform frame pair ----
    float pos0 = ((float)(k * SEG) + 0.5f) * (1.0f / 256.0f) - 0.5f;
    pos0 = fminf(fmaxf(pos0, 0.0f), (float)(NF - 1));
    const int f0 = (int)floorf(pos0);
    const int f1 = min(f0 + 1, NF - 1);

    if (tid < RES) {
        ((float*)resc0)[tid] = res[tid * NF + f0];
        ((float*)resc1)[tid] = res[tid * NF + f1];
    }

    // ---- fb prefetch for phase 2 (independent of LDS) ----
    const int b  = tid >> 7;        // 0..7
    const int sl = tid & 127;       // 0..127
    const int s  = k * SEG + sl;
    float pf[8];
    #pragma unroll
    for (int c = 0; c < 8; ++c) pf[c] = fb[c * NS + s];

    __syncthreads();   // resc ready

    // ---- Phase 1: online softmax + dual res-dot, thread tid owns row tid ----
    const float4* __restrict__ x4 = (const float4*)(x + tid * RES);
    const float4* __restrict__ g4 = (const float4*)(gn + tid * RES);

    float m = -3.0e38f, sum = 0.f, d0 = 0.f, d1 = 0.f;
    #pragma unroll
    for (int j = 0; j < RES / 4; ++j) {
        const float4 a  = x4[j];
        const float4 bb = g4[j];
        const float v0 = a.x + bb.x, v1 = a.y + bb.y;
        const float v2 = a.z + bb.z, v3 = a.w + bb.w;
        const float mc = fmaxf(fmaxf(v0, v1), fmaxf(v2, v3));
        const float mn = fmaxf(m, mc);
        const float sc = __expf(m - mn);          // 0 on first iter
        const float e0 = __expf(v0 - mn), e1 = __expf(v1 - mn);
        const float e2 = __expf(v2 - mn), e3 = __expf(v3 - mn);
        const float4 c0 = resc0[j];
        const float4 c1 = resc1[j];
        sum = fmaf(sum, sc, ((e0 + e1) + (e2 + e3)));
        float t0 = fmaf(e0, c0.x, fmaf(e1, c0.y, fmaf(e2, c0.z, e3 * c0.w)));
        float t1 = fmaf(e0, c1.x, fmaf(e1, c1.y, fmaf(e2, c1.z, e3 * c1.w)));
        d0 = fmaf(d0, sc, t0);
        d1 = fmaf(d1, sc, t1);
        m = mn;
    }
    const float inv = 1.0f / sum;
    const float r0 = d0 * inv;
    const float r1 = d1 * inv;
    r_s[tid]  = r0;
    dd_s[tid] = r1 - r0;
    __syncthreads();

    // ---- Phase 2: thread = (b, sample); wave reads 256B coalesced fb ----
    float pos = ((float)s + 0.5f) * (1.0f / 256.0f) - 0.5f;
    pos = fminf(fmaxf(pos, 0.0f), (float)(NF - 1));
    const float w = pos - (float)f0;

    const float* __restrict__ rl = &r_s[b * BANDS];
    const float* __restrict__ dp = &dd_s[b * BANDS];

    float acc = 0.f;
    #pragma unroll
    for (int c = 0; c < 8; ++c)
        acc = fmaf(pf[c], fmaf(w, dp[c], rl[c]), acc);

    #pragma unroll 8
    for (int c = 8; c < BANDS; c += 4) {
        const float fb0 = fb[(c + 0) * NS + s];
        const float fb1 = fb[(c + 1) * NS + s];
        const float fb2 = fb[(c + 2) * NS + s];
        const float fb3 = fb[(c + 3) * NS + s];
        const float4 rr = *(const float4*)&rl[c];
        const float4 dd = *(const float4*)&dp[c];
        acc = fmaf(fb0, fmaf(w, dd.x, rr.x), acc);
        acc = fmaf(fb1, fmaf(w, dd.y, rr.y), acc);
        acc = fmaf(fb2, fmaf(w, dd.z, rr.z), acc);
        acc = fmaf(fb3, fmaf(w, dd.w, rr.w), acc);
    }

    out[b * NS + s] = acc * (1.0f / (float)BANDS);
}

extern "C" void kernel_launch(void* const* d_in, const int* in_sizes, int n_in,
                              void* d_out, int out_size, void* d_ws, size_t ws_size,
                              hipStream_t stream) {
    const float* x   = (const float*)d_in[0];
    const float* gn  = (const float*)d_in[1];
    const float* fb  = (const float*)d_in[2];
    const float* res = (const float*)d_in[3];
    float* out = (float*)d_out;

    fused<<<NBLK, NTHR, 0, stream>>>(x, gn, fb, res, out);
}

// Round 8
// 18.498 us; speedup vs baseline: 1.8241x; 1.8241x over previous
//
#include <hip/hip_runtime.h>
#include <hip/hip_bf16.h>

// Shapes: x,gn (8,128,64) f32; fb (1,128,32768) f32; resonance (64,128) f32.
// out (8,1,32768) f32.
// r[b,c,f] = sum_rr softmax(x+gn)[b,c,rr] * res[rr,f]
// out[b,s] = (1/128) * sum_c lerp(r[b,c,:], s) * fb[c,s]
//
// Two kernels. Redundant-recompute fusions (R2/R5/R7) all cost ~134 MB of
// L2/L3 re-read traffic ~= +15us: dead end. R4 grid barrier: dead end.
// R8 fix: kB was LDS-issue-bound (64 ds_read_b128/thread at 16 waves/CU
// ~= 5.1us/CU). Now each thread covers 4 consecutive samples -> LDS reads
// amortized 4x (1.3us/CU), fb loaded as float4 over samples (coalesced,
// 4x fewer VMEM instrs). kB becomes HBM-bound (~2.6us/CU floor).

#define BATCH 8
#define BANDS 128
#define RES 64
#define NF 128
#define NS 32768
#define NBC (BATCH * BANDS)   // 1024
#define SEGB 128              // samples per kB block
#define NBLKB (NS / SEGB)     // 256 blocks = 1 per CU

// ---------------- Kernel A: softmax + matvec -> rT[f][b*128+c] ----------------
__global__ __launch_bounds__(64) void kA(const float* __restrict__ x,
                                         const float* __restrict__ gn,
                                         const float* __restrict__ res,
                                         float* __restrict__ rT) {
    const int bc = blockIdx.x;        // b*128 + c, 0..1023
    const int t  = threadIdx.x;       // 0..63 (one full wave)

    float v = x[bc * RES + t] + gn[bc * RES + t];

    float m = v;
    #pragma unroll
    for (int off = 32; off > 0; off >>= 1)
        m = fmaxf(m, __shfl_xor(m, off));
    const float e = expf(v - m);
    float ssum = e;
    #pragma unroll
    for (int off = 32; off > 0; off >>= 1)
        ssum += __shfl_xor(ssum, off);
    const float g = e / ssum;

    __shared__ float gs[RES];
    gs[t] = g;
    __syncthreads();

    float r0 = 0.f, r1 = 0.f;
    #pragma unroll 8
    for (int rr = 0; rr < RES; ++rr) {
        const float gg = gs[rr];
        r0 = fmaf(gg, res[rr * NF + t], r0);
        r1 = fmaf(gg, res[rr * NF + t + 64], r1);
    }
    rT[t * NBC + bc]        = r0;
    rT[(t + 64) * NBC + bc] = r1;
}

// ---------------- Kernel B: interp + fb dot + band mean ----------------
// Block k: samples [128k, 128k+127], all 8 batches. 256 threads:
// b = tid>>5, sl = tid&31; thread covers samples s0..s0+3 (s0 = 128k+4*sl).
// floor(pos) is block-uniform for 128-sample segments (pos range is
// [m-0.498, m-0.002] or [m+0.002, m+0.498]) -> stage rlo + dd in LDS once.
// fb read as float4 over samples: half-wave = 512B contiguous; the two
// half-waves (b0,b1) read identical addresses (merged). LDS rl/dp read once
// per 4-band chunk, reused for 4 samples.
__global__ __launch_bounds__(256) void kB(const float* __restrict__ fb,
                                          const float* __restrict__ rT,
                                          float* __restrict__ out) {
    const int k   = blockIdx.x;       // 0..255
    const int tid = threadIdx.x;      // 0..255
    const int b   = tid >> 5;         // 0..7
    const int sl  = tid & 31;         // 0..31
    const int s0  = k * SEGB + sl * 4;

    __shared__ float rlo_s[NBC];
    __shared__ float dd_s[NBC];

    float pos0 = ((float)(k * SEGB) + 0.5f) * (1.0f / 256.0f) - 0.5f;
    pos0 = fminf(fmaxf(pos0, 0.0f), (float)(NF - 1));
    const int lo0 = (int)floorf(pos0);        // block-uniform
    const int f1  = min(lo0 + 1, NF - 1);

    for (int i = tid; i < NBC; i += 256) {
        const float a  = rT[lo0 * NBC + i];
        const float bb = rT[f1  * NBC + i];
        rlo_s[i] = a;
        dd_s[i]  = bb - a;
    }
    __syncthreads();

    // per-sample interpolation weights
    float w0, w1, w2, w3;
    {
        float p = ((float)s0 + 0.5f) * (1.0f / 256.0f) - 0.5f;
        p = fminf(fmaxf(p, 0.0f), (float)(NF - 1));
        w0 = p - (float)lo0;
        w1 = w0 + (1.0f / 256.0f);
        w2 = w0 + (2.0f / 256.0f);
        w3 = w0 + (3.0f / 256.0f);
    }

    const float* __restrict__ rl = &rlo_s[b * BANDS];
    const float* __restrict__ dp = &dd_s[b * BANDS];

    float a0 = 0.f, a1 = 0.f, a2 = 0.f, a3 = 0.f;
    #pragma unroll 4
    for (int c = 0; c < BANDS; c += 4) {
        const float4 rr4 = *(const float4*)&rl[c];
        const float4 dd4 = *(const float4*)&dp[c];

        const float4 f0 = *(const float4*)&fb[(c + 0) * NS + s0];
        const float4 f1v = *(const float4*)&fb[(c + 1) * NS + s0];
        const float4 f2 = *(const float4*)&fb[(c + 2) * NS + s0];
        const float4 f3 = *(const float4*)&fb[(c + 3) * NS + s0];

        // band c+0
        a0 = fmaf(f0.x, fmaf(w0, dd4.x, rr4.x), a0);
        a1 = fmaf(f0.y, fmaf(w1, dd4.x, rr4.x), a1);
        a2 = fmaf(f0.z, fmaf(w2, dd4.x, rr4.x), a2);
        a3 = fmaf(f0.w, fmaf(w3, dd4.x, rr4.x), a3);
        // band c+1
        a0 = fmaf(f1v.x, fmaf(w0, dd4.y, rr4.y), a0);
        a1 = fmaf(f1v.y, fmaf(w1, dd4.y, rr4.y), a1);
        a2 = fmaf(f1v.z, fmaf(w2, dd4.y, rr4.y), a2);
        a3 = fmaf(f1v.w, fmaf(w3, dd4.y, rr4.y), a3);
        // band c+2
        a0 = fmaf(f2.x, fmaf(w0, dd4.z, rr4.z), a0);
        a1 = fmaf(f2.y, fmaf(w1, dd4.z, rr4.z), a1);
        a2 = fmaf(f2.z, fmaf(w2, dd4.z, rr4.z), a2);
        a3 = fmaf(f2.w, fmaf(w3, dd4.z, rr4.z), a3);
        // band c+3
        a0 = fmaf(f3.x, fmaf(w0, dd4.w, rr4.w), a0);
        a1 = fmaf(f3.y, fmaf(w1, dd4.w, rr4.w), a1);
        a2 = fmaf(f3.z, fmaf(w2, dd4.w, rr4.w), a2);
        a3 = fmaf(f3.w, fmaf(w3, dd4.w, rr4.w), a3);
    }

    const float sc = 1.0f / (float)BANDS;
    float4 o;
    o.x = a0 * sc; o.y = a1 * sc; o.z = a2 * sc; o.w = a3 * sc;
    *(float4*)&out[b * NS + s0] = o;
}

extern "C" void kernel_launch(void* const* d_in, const int* in_sizes, int n_in,
                              void* d_out, int out_size, void* d_ws, size_t ws_size,
                              hipStream_t stream) {
    const float* x   = (const float*)d_in[0];
    const float* gn  = (const float*)d_in[1];
    const float* fb  = (const float*)d_in[2];
    const float* res = (const float*)d_in[3];
    float* out = (float*)d_out;
    float* rT  = (float*)d_ws;   // NF * NBC floats = 512 KB

    kA<<<NBC, 64, 0, stream>>>(x, gn, res, rT);
    kB<<<NBLKB, 256, 0, stream>>>(fb, rT, out);
}